// Round 11
// baseline (252.030 us; speedup 1.0000x reference)
//
#include <hip/hip_runtime.h>

// SoftDTW: B=64, N=512, M=512, DIM=64, GAMMA=1.0, BANDWIDTH=0, BIG=1e10
constexpr int Bc   = 64;
constexpr int Nc   = 512;
constexpr int Mc   = 512;
constexpr int DIMc = 64;
constexpr float BIGc = 1e10f;
constexpr int CELLS = Nc * Mc;          // 1 MiB/batch compact diag-major D (prescaled)
constexpr float LOG2E = 1.442695041f;
constexpr float LN2   = 0.6931471806f;

struct TrueC  { static constexpr bool value = true;  };
struct FalseC { static constexpr bool value = false; };

// compact diag storage: diag g (= n+m, 0-based) starts at diag_off(g); cell
// (row n, col m) with g=n+m lives at diag_off(g) + n - nmin(g).
__device__ __forceinline__ int diag_off(int g) {
    if (g < Mc) return g * (g + 1) / 2;
    int e = g - Mc;
    return Mc * (Mc + 1) / 2 + e * (Nc - 1) - e * (e - 1) / 2;
}
__device__ __forceinline__ int diag_nmin(int g) {
    return (g > Mc - 1) ? (g - (Mc - 1)) : 0;
}
// diag_off(g) - nmin(g): the scalar base so addr = dOffm(g) + row
__device__ __forceinline__ int dOffm(int g) {
    if (g < 512) return g * (g + 1) / 2;
    int e = g - 512;
    return 131328 + e * 511 - e * (e - 1) / 2 - (g - 511);
}

// lane l <- lane l-1 across the 64-lane wave; lane 0 <- old
__device__ __forceinline__ float dpp_shr1_f(float v, float old) {
    return __builtin_bit_cast(float, __builtin_amdgcn_update_dpp(
        __builtin_bit_cast(int, old), __builtin_bit_cast(int, v), 0x138, 0xF, 0xF, false));
}
__device__ __forceinline__ float f4c(const float4 v, int c) {
    switch (c & 3) { case 0: return v.x; case 1: return v.y;
                     case 2: return v.z; default: return v.w; }
}
__device__ __forceinline__ void f4set(float4& d, int c, float v) {
    switch (c & 3) { case 0: d.x = v; break; case 1: d.y = v; break;
                     case 2: d.z = v; break; default: d.w = v; }
}

// ---------------- Kernel A: D -> compact diag-major, 128x128 tiles, 8x8 micro ----
// LDS (dynamic): Xs[64][132] | Ys[64][132] | Ct[128][130]  = 131 KiB
constexpr int XS_OFF = 0;
constexpr int YS_OFF = 64 * 132;
constexpr int CT_OFF = 2 * 64 * 132;
constexpr int A_LDS_WORDS = CT_OFF + 128 * 130;     // 33536 words = 134144 B

__global__ __launch_bounds__(256)
void compute_D_diag(const float* __restrict__ X, const float* __restrict__ Y,
                    float* __restrict__ Dc)
{
    extern __shared__ float lds[];
    float* Xs = lds + XS_OFF;     // [k][n] stride 132
    float* Ys = lds + YS_OFF;     // [k][m] stride 132
    float* Ct = lds + CT_OFF;     // [n][m] stride 130

    const int b   = blockIdx.x;
    const int nt  = blockIdx.y;                 // 0..3 (128-row tiles)
    const int tid = threadIdx.x;
    const int ty  = tid >> 4, tx = tid & 15;    // 16x16 threads, 8x8 cells each

    const float* Xb = X + ((size_t)b * Nc + (size_t)nt * 128) * DIMc;
    const float* Yb = Y + (size_t)b * Mc * DIMc;
    float*       Db = Dc + (size_t)b * CELLS;
    const int n0 = nt * 128;

    {   // stage X tile: 128 rows x 64 dims, transposed into Xs[k][n]
        const float4* Xb4 = reinterpret_cast<const float4*>(Xb);
        for (int c4 = tid; c4 < 128 * DIMc / 4; c4 += 256) {
            float4 v = Xb4[c4];
            const int n = c4 >> 4, k0 = (c4 & 15) * 4;
            Xs[(k0+0)*132 + n] = v.x; Xs[(k0+1)*132 + n] = v.y;
            Xs[(k0+2)*132 + n] = v.z; Xs[(k0+3)*132 + n] = v.w;
        }
    }

    for (int mt = 0; mt < 4; ++mt) {
        __syncthreads();                        // Xs ready / prev Ct+Ys reads done
        {
            const float4* Yb4 = reinterpret_cast<const float4*>(Yb + (size_t)mt * 128 * DIMc);
            for (int c4 = tid; c4 < 128 * DIMc / 4; c4 += 256) {
                float4 v = Yb4[c4];
                const int m = c4 >> 4, k0 = (c4 & 15) * 4;
                Ys[(k0+0)*132 + m] = v.x; Ys[(k0+1)*132 + m] = v.y;
                Ys[(k0+2)*132 + m] = v.z; Ys[(k0+3)*132 + m] = v.w;
            }
        }
        __syncthreads();

        float acc[8][8];
        #pragma unroll
        for (int r = 0; r < 8; ++r)
            #pragma unroll
            for (int cc = 0; cc < 8; ++cc) acc[r][cc] = 0.f;

        #pragma unroll 2
        for (int k = 0; k < DIMc; ++k) {
            float4 xa = *reinterpret_cast<const float4*>(&Xs[k*132 + ty*8]);
            float4 xb = *reinterpret_cast<const float4*>(&Xs[k*132 + ty*8 + 4]);
            float4 ya = *reinterpret_cast<const float4*>(&Ys[k*132 + tx*8]);
            float4 yb = *reinterpret_cast<const float4*>(&Ys[k*132 + tx*8 + 4]);
            float xr[8] = {xa.x,xa.y,xa.z,xa.w, xb.x,xb.y,xb.z,xb.w};
            float yr[8] = {ya.x,ya.y,ya.z,ya.w, yb.x,yb.y,yb.z,yb.w};
            #pragma unroll
            for (int r = 0; r < 8; ++r)
                #pragma unroll
                for (int cc = 0; cc < 8; ++cc) {
                    float d = xr[r] - yr[cc];
                    acc[r][cc] = fmaf(d, d, acc[r][cc]);
                }
        }

        // write micro-tile to Ct (prescaled by log2e)
        #pragma unroll
        for (int r = 0; r < 8; ++r) {
            float4 s0 = make_float4(acc[r][0]*LOG2E, acc[r][1]*LOG2E,
                                    acc[r][2]*LOG2E, acc[r][3]*LOG2E);
            float4 s1 = make_float4(acc[r][4]*LOG2E, acc[r][5]*LOG2E,
                                    acc[r][6]*LOG2E, acc[r][7]*LOG2E);
            *reinterpret_cast<float4*>(&Ct[(ty*8+r)*130 + tx*8])     = s0;
            *reinterpret_cast<float4*>(&Ct[(ty*8+r)*130 + tx*8 + 4]) = s1;
        }
        __syncthreads();

        // epilogue: 255 tile-diagonals -> contiguous global segments
        const int grp  = tid >> 6;              // 4 groups of 64 lanes
        const int lane = tid & 63;
        const int g00  = n0 + mt * 128;         // diag of tile cell (0,0)
        for (int d = grp; d < 255; d += 4) {
            const int tn_lo = max(0, d - 127);
            const int tn_hi = min(127, d);
            const int len   = tn_hi - tn_lo + 1;
            const int dg    = g00 + d;
            const int base  = diag_off(dg) - diag_nmin(dg) + n0;   // + global row
            for (int o = lane; o < len; o += 64) {
                const int tn = tn_lo + o;
                Db[base + tn] = Ct[tn*130 + (d - tn)];
            }
        }
    }
}

// ---------------- Kernel B: 8-wave systolic, direct scalar-base diag loads -------
// Wave W owns rows r = 64W..64W+63 (lane = row). D is diag-major: per step one
// global_load at Dbat[sb + r] with sb a wave-uniform SALU chain (no VALU addr,
// no LDS staging). Refill-in-body targets window q+1; loads stay in flight
// across the raw barrier (lgkm drain only). Ring/skew/preload/capture logic
// identical to round 10.
__global__ __launch_bounds__(512)
void softdtw_sys8(const float* __restrict__ Dc, const int* __restrict__ lengths,
                  float* __restrict__ out)
{
    __shared__ float ring[8][64];
    const int b    = blockIdx.x;
    const int t    = threadIdx.x;
    const int lane = t & 63;
    const int W    = __builtin_amdgcn_readfirstlane(t >> 6);   // scalar 0..7
    const int L    = lengths[b];
    const int r    = (W << 6) + lane;       // 0-based row
    const int i    = r + 1;
    const float* Dbat = Dc + (size_t)b * CELLS;

    if (t < 64) ring[0][t] = BIGc;          // ring[0] (no writer)
    __syncthreads();

    const bool l0   = (lane == 0);
    const bool iok  = (i <= L);
    const int  gcap = (i == L) ? (L + 510) : -1;   // diag of result cell
    const int  qlL  = (L + 510) >> 5;              // last needed window
    const bool rowsOK = ((W << 6) + 64) <= L;
    const int  q0 = 2 * W;
    const int  ql = min(2 * W + 17, qlL);
    const int  cmax = 8 + qlL;

    float own = BIGc, nb1 = BIGc, nb2 = BIGc, res = 0.f;
    if (W == 0 && l0) nb2 = 0.f;            // R[0][0] seed

    // prologue: load window q0 (all rising: g = 64W+s <= 479)
    float Dwin[32];
    {
        int sb = dOffm(q0 * 32);
        int gg = q0 * 32;
        #pragma unroll
        for (int s = 0; s < 32; ++s) {
            Dwin[s] = Dbat[sb + r];
            int d1 = (gg < 512) ? (gg + 1) : (1023 - gg);
            sb += d1 - ((gg >= 511) ? 1 : 0);
            ++gg;
        }
    }

    for (int c = 0; c < cmax; ++c) {
        const int q = c - W;
        if (q >= q0 && q <= ql) {
            const int g0 = q * 32;

            // ring window in (uniform broadcast b128 reads, off the chain)
            float4 rv[8];
            {
                const float4* rp = reinterpret_cast<const float4*>(&ring[W][g0 & 63]);
                #pragma unroll
                for (int u = 0; u < 8; ++u) rv[u] = rp[u];
            }

            // scalar base chain for next-window refills (harmless g=0 if done)
            const bool doNext = (q + 1 <= ql);
            int gN  = doNext ? (g0 + 32) : 0;
            int sbN = dOffm(gN);

            float4 expv[8];                 // packed boundary values for ring export
            const bool fastC = rowsOK && q >= q0 + 2 && q <= q0 + 15 && q != qlL;

            auto body = [&](auto FASTC) {
                constexpr bool FAST = decltype(FASTC)::value;
                #pragma unroll
                for (int s = 0; s < 32; ++s) {
                    const int g = g0 + s;
                    const float mn = fminf(nb2, fminf(nb1, own));
                    const float e  = __builtin_amdgcn_exp2f(mn - nb2)
                                   + __builtin_amdgcn_exp2f(mn - nb1)
                                   + __builtin_amdgcn_exp2f(mn - own);
                    const float sm = mn - __builtin_amdgcn_logf(e);   // log2
                    float v = Dwin[s] + sm;
                    if (!FAST) {
                        const bool jok = (unsigned)(g - r) < (unsigned)Mc;
                        v = (jok && iok) ? v : BIGc;
                        res = (g == gcap) ? v : res;   // capture (always slow window)
                    }
                    // refill slot s from window q+1 (scalar base + constant r)
                    Dwin[s] = Dbat[sbN + r];
                    {
                        int d1 = (gN < 512) ? (gN + 1) : (1023 - gN);
                        sbN += d1 - ((gN >= 511) ? 1 : 0);
                        ++gN;
                    }
                    f4set(expv[s >> 2], s, v);
                    const float sh = dpp_shr1_f(v, BIGc);
                    nb2 = nb1;
                    nb1 = l0 ? f4c(rv[s >> 2], s) : sh;
                    own = v;
                }
            };
            if (fastC) body(TrueC{}); else body(FalseC{});

            // ring export: 8x b128 from packed regs (lane 63 only)
            if (W < 7 && lane == 63) {
                float* re = &ring[W + 1][g0 & 63];
                #pragma unroll
                for (int u = 0; u < 8; ++u)
                    reinterpret_cast<float4*>(re)[u] = expv[u];
            }
        } else if (W > 0 && q == q0 - 1) {
            // ring preload replacing warm-up: after window q0-1 (odd parity,
            // slots 32..63), lane0 chain state is nb1=ring[63] (g=64W-1),
            // nb2=ring[62] (BIG by construction).
            const float p1 = ring[W][63];
            const float p0 = ring[W][62];
            nb1 = l0 ? p1 : nb1;
            nb2 = l0 ? p0 : nb2;
        }
        asm volatile("s_waitcnt lgkmcnt(0)" ::: "memory");  // ring writes visible
        __builtin_amdgcn_s_barrier();                       // no vmcnt drain
        asm volatile("" ::: "memory");
    }

    if (i == L) out[b] = res * LN2;
}

// ---------------- Fallback (no workspace): fused on-the-fly D --------------------
__global__ __launch_bounds__(512)
void softdtw_fused(const float* __restrict__ X, const float* __restrict__ Y,
                   const int* __restrict__ lengths, float* __restrict__ out)
{
    const int b = blockIdx.x;
    const int t = threadIdx.x;
    const int i = t + 1;
    const int L = lengths[b];

    __shared__ float diag[3][Nc + 1];
    for (int c = t; c <= Nc; c += 512) {
        diag[0][c] = (c == 0) ? 0.f : BIGc;
        diag[1][c] = BIGc;
    }
    float xr[DIMc];
    const float* Xrow = X + ((size_t)b * Nc + t) * DIMc;
    #pragma unroll
    for (int d = 0; d < DIMc; d += 4) {
        float4 v = *reinterpret_cast<const float4*>(Xrow + d);
        xr[d] = v.x; xr[d+1] = v.y; xr[d+2] = v.z; xr[d+3] = v.w;
    }
    const float* Yb = Y + (size_t)b * Mc * DIMc;
    __syncthreads();

    float result = BIGc;
    int cur = 2, p1 = 1, p2 = 0;
    for (int k = 2; k <= Nc + Mc; ++k) {
        const int j = k - i;
        const bool valid = (j >= 1) && (j <= Mc) && (i <= L);
        float Dval = 0.f;
        if (valid) {
            const float* Yrow = Yb + (size_t)(j - 1) * DIMc;
            float s = 0.f;
            #pragma unroll
            for (int d = 0; d < DIMc; d += 4) {
                float4 v = *reinterpret_cast<const float4*>(Yrow + d);
                float d0 = xr[d] - v.x, d1 = xr[d+1] - v.y;
                float d2 = xr[d+2] - v.z, d3 = xr[d+3] - v.w;
                s = fmaf(d0,d0,s); s = fmaf(d1,d1,s); s = fmaf(d2,d2,s); s = fmaf(d3,d3,s);
            }
            Dval = s;
        }
        const float a2 = diag[p2][i-1], a1 = diag[p1][i-1], a0 = diag[p1][i];
        const float mn = fminf(a2, fminf(a1, a0));
        const float sm = mn - __logf(__expf(mn-a2) + __expf(mn-a1) + __expf(mn-a0));
        const float val = valid ? (Dval + sm) : BIGc;
        diag[cur][i] = val;
        if (t == 0) diag[cur][0] = BIGc;
        if (k == L + Mc && i == L) result = val;
        __syncthreads();
        const int tmp = p2; p2 = p1; p1 = cur; cur = tmp;
    }
    if (i == L) out[b] = result;
}

extern "C" void kernel_launch(void* const* d_in, const int* in_sizes, int n_in,
                              void* d_out, int out_size, void* d_ws, size_t ws_size,
                              hipStream_t stream) {
    const float* X = (const float*)d_in[0];
    const float* Y = (const float*)d_in[1];
    const int* lengths = (const int*)d_in[2];
    float* out = (float*)d_out;

    const size_t need = (size_t)Bc * CELLS * sizeof(float);   // 64 MiB
    if (ws_size >= need) {
        float* Dc = (float*)d_ws;
        compute_D_diag<<<dim3(Bc, 4), 256, A_LDS_WORDS * 4, stream>>>(X, Y, Dc);
        softdtw_sys8<<<Bc, 512, 0, stream>>>(Dc, lengths, out);
    } else {
        softdtw_fused<<<Bc, 512, 0, stream>>>(X, Y, lengths, out);
    }
}

// Round 12
// 243.092 us; speedup vs baseline: 1.0368x; 1.0368x over previous
//
#include <hip/hip_runtime.h>

// SoftDTW: B=64, N=512, M=512, DIM=64, GAMMA=1.0, BANDWIDTH=0, BIG=1e10
constexpr int Bc   = 64;
constexpr int Nc   = 512;
constexpr int Mc   = 512;
constexpr int DIMc = 64;
constexpr float BIGc = 1e10f;
constexpr int CELLS = Nc * Mc;          // 1 MiB/batch compact diag-major D (prescaled)
constexpr float LOG2E = 1.442695041f;
constexpr float LN2   = 0.6931471806f;

struct TrueC  { static constexpr bool value = true;  };
struct FalseC { static constexpr bool value = false; };

// compact diag storage: diag g (= n+m, 0-based) starts at diag_off(g); cell
// (row n, col m) lives at diag_off(g) + n - nmin(g) = dOffm(g) + n.
__device__ __forceinline__ int diag_off(int g) {
    if (g < Mc) return g * (g + 1) / 2;
    int e = g - Mc;
    return Mc * (Mc + 1) / 2 + e * (Nc - 1) - e * (e - 1) / 2;
}
__device__ __forceinline__ int diag_nmin(int g) {
    return (g > Mc - 1) ? (g - (Mc - 1)) : 0;
}
__device__ __forceinline__ int dOffm(int g) {
    if (g < 512) return g * (g + 1) / 2;
    int e = g - 512;
    return 131328 + e * 511 - e * (e - 1) / 2 - (g - 511);
}

// lane l <- lane l-1 across the 64-lane wave; lane 0 <- old
__device__ __forceinline__ float dpp_shr1_f(float v, float old) {
    return __builtin_bit_cast(float, __builtin_amdgcn_update_dpp(
        __builtin_bit_cast(int, old), __builtin_bit_cast(int, v), 0x138, 0xF, 0xF, false));
}
__device__ __forceinline__ float f4c(const float4 v, int c) {
    switch (c & 3) { case 0: return v.x; case 1: return v.y;
                     case 2: return v.z; default: return v.w; }
}
__device__ __forceinline__ void f4set(float4& d, int c, float v) {
    switch (c & 3) { case 0: d.x = v; break; case 1: d.y = v; break;
                     case 2: d.z = v; break; default: d.w = v; }
}

// ---------------- Kernel A: D -> compact diag-major, 64x64 tiles + Ct staging ----
// (round-3 proven structure; 51.7 KB static LDS -> 2 blocks/CU; prescale log2e)
__global__ __launch_bounds__(256)
void compute_D_diag(const float* __restrict__ X, const float* __restrict__ Y,
                    float* __restrict__ Dc)
{
    const int b   = blockIdx.x;
    const int nt  = blockIdx.y;          // 64-row n tile (8 of them)
    const int tid = threadIdx.x;
    const int ty  = tid >> 4, tx = tid & 15;

    __shared__ float Xs[DIMc][68];       // [dim][row], padded
    __shared__ float Ys[DIMc][68];
    __shared__ float Ct[64][66];         // output staging (stride 66 -> diag reads clean)

    const float* Xb = X + ((size_t)b * Nc + (size_t)nt * 64) * DIMc;
    const float* Yb = Y + (size_t)b * Mc * DIMc;
    float*       Db = Dc + (size_t)b * CELLS;
    const int n0 = nt * 64;

    {
        const float4* Xb4 = reinterpret_cast<const float4*>(Xb);
        for (int c4 = tid; c4 < 64 * DIMc / 4; c4 += 256) {
            float4 v = Xb4[c4];
            const int n = c4 >> 4, k0 = (c4 & 15) * 4;
            Xs[k0+0][n] = v.x; Xs[k0+1][n] = v.y; Xs[k0+2][n] = v.z; Xs[k0+3][n] = v.w;
        }
    }

    for (int mt = 0; mt < Mc / 64; ++mt) {
        __syncthreads();                 // Xs ready / prev Ys+Ct reads done
        {
            const float4* Yb4 = reinterpret_cast<const float4*>(Yb + (size_t)mt * 64 * DIMc);
            for (int c4 = tid; c4 < 64 * DIMc / 4; c4 += 256) {
                float4 v = Yb4[c4];
                const int n = c4 >> 4, k0 = (c4 & 15) * 4;
                Ys[k0+0][n] = v.x; Ys[k0+1][n] = v.y; Ys[k0+2][n] = v.z; Ys[k0+3][n] = v.w;
            }
        }
        __syncthreads();

        float acc[4][4];
        #pragma unroll
        for (int r = 0; r < 4; ++r)
            #pragma unroll
            for (int cc = 0; cc < 4; ++cc) acc[r][cc] = 0.f;

        #pragma unroll 8
        for (int k = 0; k < DIMc; ++k) {
            float4 xv = *reinterpret_cast<const float4*>(&Xs[k][ty * 4]);
            float4 yv = *reinterpret_cast<const float4*>(&Ys[k][tx * 4]);
            float xr[4] = {xv.x, xv.y, xv.z, xv.w};
            float yr[4] = {yv.x, yv.y, yv.z, yv.w};
            #pragma unroll
            for (int r = 0; r < 4; ++r)
                #pragma unroll
                for (int cc = 0; cc < 4; ++cc) {
                    float d = xr[r] - yr[cc];
                    acc[r][cc] = fmaf(d, d, acc[r][cc]);
                }
        }

        #pragma unroll
        for (int r = 0; r < 4; ++r)
            #pragma unroll
            for (int cc = 0; cc < 4; ++cc)
                Ct[ty * 4 + r][tx * 4 + cc] = acc[r][cc] * LOG2E;
        __syncthreads();

        // 127 tile-diagonals -> contiguous global segments (coalesced)
        const int grp  = tid >> 6;       // 4 groups of 64 lanes
        const int lane = tid & 63;
        const int m0   = mt * 64;
        for (int d = grp; d < 127; d += 4) {
            const int tn_lo = max(0, d - 63);
            const int tn_hi = min(63, d);
            if (lane <= tn_hi - tn_lo) {
                const int tn = tn_lo + lane;
                const int dg = n0 + m0 + d;
                Db[dOffm(dg) + n0 + tn] = Ct[tn][d - tn];
            }
        }
    }
}

// ---------------- Kernel B: 4-wave systolic, 2 rows/thread -----------------------
// Wave W owns rows 128W..128W+127; lane owns rA=128W+2*lane, rB=rA+1. Per step g
// compute cells (rA,g),(rB,g) IN PARALLEL off state {A1,B1,A2,nb1,nb2} (one
// softmin-depth per step for 2 rows -> chain/cell halves vs 1-row). One DPP +
// one ring export per step covers both rows. D is diag-major: 2 adjacent dword
// loads at scalar base sb (SALU chain) + constant rA. 1 wave/SIMD.
__global__ __launch_bounds__(256)
void softdtw_sys4(const float* __restrict__ Dc, const int* __restrict__ lengths,
                  float* __restrict__ out)
{
    __shared__ float ring[4][64];
    const int b    = blockIdx.x;
    const int t    = threadIdx.x;
    const int lane = t & 63;
    const int W    = __builtin_amdgcn_readfirstlane(t >> 6);   // scalar 0..3
    const int L    = lengths[b];
    const int rA   = (W << 7) + (lane << 1);   // 0-based rows
    const int rB   = rA + 1;
    const float* Dbat = Dc + (size_t)b * CELLS;

    if (t < 64) ring[0][t] = BIGc;      // ring[0] has no writer
    __syncthreads();

    const bool l0    = (lane == 0);
    const bool iokA  = (rA <= L - 1);
    const bool iokB  = (rB <= L - 1);
    const int  gcapA = (rA == L - 1) ? (rA + 511) : -1;
    const int  gcapB = (rB == L - 1) ? (rB + 511) : -1;
    const int  qlL   = (L + 510) >> 5;           // window of the result diag
    const bool rowsOK = ((W << 7) + 128) <= L;
    const int  q0 = 4 * W;
    const int  ql = min(4 * W + 19, qlL);
    const int  cmax = qlL + 4;

    float A1 = BIGc, B1 = BIGc, A2 = BIGc, nb1 = BIGc, nb2 = BIGc, res = 0.f;
    if (W == 0 && l0) nb2 = 0.f;        // DP origin seed for cell (0,0)

    // prologue: load window q0 (g = 128W+s, rising region)
    float2 Dwin[32];
    {
        int sb = dOffm(q0 * 32);
        int gg = q0 * 32;
        #pragma unroll
        for (int s = 0; s < 32; ++s) {
            Dwin[s].x = Dbat[sb + rA];
            Dwin[s].y = Dbat[sb + rA + 1];
            int d1 = (gg < 512) ? (gg + 1) : (1023 - gg);
            sb += d1 - ((gg >= 511) ? 1 : 0);
            ++gg;
        }
    }

    for (int c = 0; c < cmax; ++c) {
        const int q = c - W;
        if (q >= q0 && q <= ql) {
            const int g0 = q * 32;

            // ring window in (uniform broadcast b128 reads, off the chain)
            float4 rv[8];
            {
                const float4* rp = reinterpret_cast<const float4*>(&ring[W][g0 & 63]);
                #pragma unroll
                for (int u = 0; u < 8; ++u) rv[u] = rp[u];
            }

            const bool doNext = (q + 1 <= ql);
            int gN  = doNext ? (g0 + 32) : 0;
            int sbN = dOffm(gN);

            float4 expv[8];
            // fast (all cells interior & below L): q in [4W+4, 4W+15]
            const bool fastC = rowsOK && q >= q0 + 4 && q <= q0 + 15 && q != qlL;

            auto body = [&](auto FASTC) {
                constexpr bool FAST = decltype(FASTC)::value;
                #pragma unroll
                for (int s = 0; s < 32; ++s) {
                    const int g = g0 + s;
                    // cell (rB,g): up=A1, left=B1, diag=A2  (all thread-local)
                    const float mnB = fminf(A2, fminf(A1, B1));
                    const float eB  = __builtin_amdgcn_exp2f(mnB - A2)
                                    + __builtin_amdgcn_exp2f(mnB - A1)
                                    + __builtin_amdgcn_exp2f(mnB - B1);
                    float vB = Dwin[s].y + (mnB - __builtin_amdgcn_logf(eB));
                    // cell (rA,g): up=nb1, left=A1, diag=nb2  (parallel with B)
                    const float mnA = fminf(nb2, fminf(nb1, A1));
                    const float eA  = __builtin_amdgcn_exp2f(mnA - nb2)
                                    + __builtin_amdgcn_exp2f(mnA - nb1)
                                    + __builtin_amdgcn_exp2f(mnA - A1);
                    float vA = Dwin[s].x + (mnA - __builtin_amdgcn_logf(eA));
                    if (!FAST) {
                        const bool jA = (unsigned)(g - rA) < (unsigned)Mc;
                        const bool jB = (unsigned)(g - rB) < (unsigned)Mc;
                        vA = (jA && iokA) ? vA : BIGc;
                        vB = (jB && iokB) ? vB : BIGc;
                        res = (g == gcapA) ? vA : res;
                        res = (g == gcapB) ? vB : res;
                    }
                    // refill slot s from window q+1 (scalar base + constant rA)
                    Dwin[s].x = Dbat[sbN + rA];
                    Dwin[s].y = Dbat[sbN + rA + 1];
                    {
                        int d1 = (gN < 512) ? (gN + 1) : (1023 - gN);
                        sbN += d1 - ((gN >= 511) ? 1 : 0);
                        ++gN;
                    }
                    f4set(expv[s >> 2], s, vB);
                    const float sh = dpp_shr1_f(vB, BIGc);
                    A2 = A1; A1 = vA; B1 = vB;
                    nb2 = nb1;
                    nb1 = l0 ? f4c(rv[s >> 2], s) : sh;
                }
            };
            if (fastC) body(TrueC{}); else body(FalseC{});

            // ring export: 8x b128 from packed regs (lane 63 only)
            if (W < 3 && lane == 63) {
                float* re = &ring[W + 1][g0 & 63];
                #pragma unroll
                for (int u = 0; u < 8; ++u)
                    reinterpret_cast<float4*>(re)[u] = expv[u];
            }
        } else if (W > 0 && q == q0 - 1) {
            // preload replacing warm-up: slots 62/63 of previous parity hold
            // R[128W-1][128W-2] (=BIG) and R[128W-1][128W-1]
            const float p1 = ring[W][63];
            const float p0 = ring[W][62];
            nb1 = l0 ? p1 : nb1;
            nb2 = l0 ? p0 : nb2;
        }
        asm volatile("s_waitcnt lgkmcnt(0)" ::: "memory");  // ring writes visible
        __builtin_amdgcn_s_barrier();                       // no vmcnt drain
        asm volatile("" ::: "memory");
    }

    if (rA == L - 1 || rB == L - 1) out[b] = res * LN2;
}

// ---------------- Fallback (no workspace): fused on-the-fly D --------------------
__global__ __launch_bounds__(512)
void softdtw_fused(const float* __restrict__ X, const float* __restrict__ Y,
                   const int* __restrict__ lengths, float* __restrict__ out)
{
    const int b = blockIdx.x;
    const int t = threadIdx.x;
    const int i = t + 1;
    const int L = lengths[b];

    __shared__ float diag[3][Nc + 1];
    for (int c = t; c <= Nc; c += 512) {
        diag[0][c] = (c == 0) ? 0.f : BIGc;
        diag[1][c] = BIGc;
    }
    float xr[DIMc];
    const float* Xrow = X + ((size_t)b * Nc + t) * DIMc;
    #pragma unroll
    for (int d = 0; d < DIMc; d += 4) {
        float4 v = *reinterpret_cast<const float4*>(Xrow + d);
        xr[d] = v.x; xr[d+1] = v.y; xr[d+2] = v.z; xr[d+3] = v.w;
    }
    const float* Yb = Y + (size_t)b * Mc * DIMc;
    __syncthreads();

    float result = BIGc;
    int cur = 2, p1 = 1, p2 = 0;
    for (int k = 2; k <= Nc + Mc; ++k) {
        const int j = k - i;
        const bool valid = (j >= 1) && (j <= Mc) && (i <= L);
        float Dval = 0.f;
        if (valid) {
            const float* Yrow = Yb + (size_t)(j - 1) * DIMc;
            float s = 0.f;
            #pragma unroll
            for (int d = 0; d < DIMc; d += 4) {
                float4 v = *reinterpret_cast<const float4*>(Yrow + d);
                float d0 = xr[d] - v.x, d1 = xr[d+1] - v.y;
                float d2 = xr[d+2] - v.z, d3 = xr[d+3] - v.w;
                s = fmaf(d0,d0,s); s = fmaf(d1,d1,s); s = fmaf(d2,d2,s); s = fmaf(d3,d3,s);
            }
            Dval = s;
        }
        const float a2 = diag[p2][i-1], a1 = diag[p1][i-1], a0 = diag[p1][i];
        const float mn = fminf(a2, fminf(a1, a0));
        const float sm = mn - __logf(__expf(mn-a2) + __expf(mn-a1) + __expf(mn-a0));
        const float val = valid ? (Dval + sm) : BIGc;
        diag[cur][i] = val;
        if (t == 0) diag[cur][0] = BIGc;
        if (k == L + Mc && i == L) result = val;
        __syncthreads();
        const int tmp = p2; p2 = p1; p1 = cur; cur = tmp;
    }
    if (i == L) out[b] = result;
}

extern "C" void kernel_launch(void* const* d_in, const int* in_sizes, int n_in,
                              void* d_out, int out_size, void* d_ws, size_t ws_size,
                              hipStream_t stream) {
    const float* X = (const float*)d_in[0];
    const float* Y = (const float*)d_in[1];
    const int* lengths = (const int*)d_in[2];
    float* out = (float*)d_out;

    const size_t need = (size_t)Bc * CELLS * sizeof(float);   // 64 MiB
    if (ws_size >= need) {
        float* Dc = (float*)d_ws;
        compute_D_diag<<<dim3(Bc, Nc / 64), 256, 0, stream>>>(X, Y, Dc);
        softdtw_sys4<<<Bc, 256, 0, stream>>>(Dc, lengths, out);
    } else {
        softdtw_fused<<<Bc, 512, 0, stream>>>(X, Y, lengths, out);
    }
}